// Round 21
// baseline (133.458 us; speedup 1.0000x reference)
//
#include <hip/hip_runtime.h>
#include <hip/hip_bf16.h>

using f32x4  = __attribute__((ext_vector_type(4))) float;
using bf16x8 = __attribute__((ext_vector_type(8))) short;
using i32x4  = __attribute__((ext_vector_type(4))) int;

static constexpr float SCALE = 0.17677669529663687f; // 32^-0.5
static constexpr float L2E   = 1.4426950408889634f;
static constexpr float SL    = SCALE * L2E;

__device__ inline int cvtpk(float lo, float hi) {
  int r;
  asm("v_cvt_pk_bf16_f32 %0,%1,%2" : "=v"(r) : "v"(lo), "v"(hi));
  return r;
}

// ---- wave+block reduce (sum, sumsq), 256-thread blocks --------------------
__device__ inline void bred2(float& s, float& ss) {
  #pragma unroll
  for (int off = 32; off; off >>= 1) {
    s  += __shfl_down(s, off, 64);
    ss += __shfl_down(ss, off, 64);
  }
  __shared__ float as_[4], ass_[4];
  int wid = threadIdx.x >> 6;
  if ((threadIdx.x & 63) == 0) { as_[wid] = s; ass_[wid] = ss; }
  __syncthreads();
  s  = as_[0] + as_[1] + as_[2] + as_[3];
  ss = ass_[0] + ass_[1] + ass_[2] + ass_[3];
}

// ---- K1: BN stats for x1 and x2 -------------------------------------------
__global__ __launch_bounds__(256) void bnstat_both_kernel(
    const float* __restrict__ x1, const float* __restrict__ x2,
    const float* __restrict__ gl, const float* __restrict__ bl,
    const float* __restrict__ gh, const float* __restrict__ bh,
    float* __restrict__ ab_l, float* __restrict__ ab_h) {
  int b = blockIdx.x;
  const float* src; const float *gamma, *beta; float* ab; int S, C, c;
  if (b < 256) { c = b;       src = x1 + (size_t)c * 512;  S = 512;  C = 256; gamma = gl; beta = bl; ab = ab_l; }
  else         { c = b - 256; src = x2 + (size_t)c * 4096; S = 4096; C = 128; gamma = gh; beta = bh; ab = ab_h; }
  float s = 0.f, ss = 0.f;
  for (int i = threadIdx.x; i < S; i += 256) { float v = src[i]; s += v; ss = fmaf(v, v, ss); }
  bred2(s, ss);
  if (threadIdx.x == 0) {
    float inv = 1.0f / (float)S;
    float m   = s * inv;
    float var = ss * inv - m * m;
    float a   = gamma[c] * rsqrtf(var + 1e-5f);
    ab[c]     = a;
    ab[C + c] = beta[c] - m * a;
  }
}

// ---- depthwise 3x3x3, 2 x-adjacent outputs per thread ---------------------
template<bool AFF>
__device__ inline void dw_body2(
    const float* __restrict__ in, const float* __restrict__ w,
    const float* __restrict__ ab, float* __restrict__ out,
    int n, int nn, int n3, int C, int t2) {
  int half = n3 >> 1;
  int c  = t2 / half;
  int sp = (t2 - c * half) * 2;            // even spatial index
  int z = sp / nn, r = sp - z * nn, y = r / n, x = r - y * n;  // x even
  const float* src = in + (size_t)c * n3;
  const float* wc  = w + c * 27;
  float a = 1.f, b = 0.f;
  if (AFF) { a = ab[c]; b = ab[C + c]; }
  float acc0 = 0.f, acc1 = 0.f;
  #pragma unroll
  for (int kd = 0; kd < 3; kd++) {
    int zz = z + kd - 1;
    if (zz < 0 || zz >= n) continue;
    #pragma unroll
    for (int kh = 0; kh < 3; kh++) {
      int yy = y + kh - 1;
      if (yy < 0 || yy >= n) continue;
      const float* row = src + (zz * n + yy) * n;
      const float* wr  = wc + kd * 9 + kh * 3;
      float v1 = row[x];
      float v2 = row[x + 1];
      float v0 = (x >= 1)     ? row[x - 1] : 0.f;
      float v3 = (x + 2 < n)  ? row[x + 2] : 0.f;
      if (AFF) {
        if (x >= 1)    v0 = fmaf(v0, a, b);
        v1 = fmaf(v1, a, b);
        v2 = fmaf(v2, a, b);
        if (x + 2 < n) v3 = fmaf(v3, a, b);
      }
      float w0 = wr[0], w1 = wr[1], w2 = wr[2];
      acc0 = fmaf(v0, w0, fmaf(v1, w1, fmaf(v2, w2, acc0)));
      acc1 = fmaf(v1, w0, fmaf(v2, w1, fmaf(v3, w2, acc1)));
    }
  }
  out[(size_t)c * n3 + sp]     = acc0;
  out[(size_t)c * n3 + sp + 1] = acc1;
}

// ---- K2: stageA = res8 pointwise | dw_kv | dw_q ---------------------------
__global__ __launch_bounds__(256) void stageA_kernel(
    const float* __restrict__ x1, const float* __restrict__ x2,
    const float* __restrict__ w_ch, const float* __restrict__ b_ch,
    const float* __restrict__ kv_dw, const float* __restrict__ q_dw,
    const float* __restrict__ ab_l, const float* __restrict__ ab_h,
    float* __restrict__ res8, float* __restrict__ kvdw, float* __restrict__ qdw) {
  int b = blockIdx.x;
  if (b < 128) {
    int oc0 = (b >> 1) * 2;
    int s   = (b & 1) * 256 + threadIdx.x;
    float a0 = 0.f, a1 = 0.f;
    const float* w0 = w_ch + (size_t)oc0 * 256;
    const float* w1 = w0 + 256;
    #pragma unroll 8
    for (int ic = 0; ic < 256; ic++) {
      float x = x1[(size_t)ic * 512 + s];
      a0 = fmaf(w0[ic], x, a0);
      a1 = fmaf(w1[ic], x, a1);
    }
    res8[(size_t)oc0 * 512 + s]       = a0 + b_ch[oc0];
    res8[(size_t)(oc0 + 1) * 512 + s] = a1 + b_ch[oc0 + 1];
  } else if (b < 384) {
    dw_body2<true>(x1, kv_dw, ab_l, kvdw, 8, 64, 512, 256, (b - 128) * 256 + threadIdx.x);
  } else {
    dw_body2<true>(x2, q_dw, ab_h, qdw, 16, 256, 4096, 128, (b - 384) * 256 + threadIdx.x);
  }
}

// ---- trilinear helpers ----------------------------------------------------
__device__ inline void icoef8(int o, int& lo, int& hi, float& w) {
  float p = (float)o * (7.0f / 15.0f);
  int l = (int)floorf(p);
  if (l > 7) l = 7;
  int h = l + 1 > 7 ? 7 : l + 1;
  w  = p - (float)l;
  lo = l; hi = h;
}

__device__ inline float trilin8(const float* __restrict__ p,
                                int z0, int z1, float wz,
                                int y0, int y1, float wy,
                                int x0, int x1, float wx) {
  float c00 = p[(z0*8+y0)*8+x0]*(1.f-wx) + p[(z0*8+y0)*8+x1]*wx;
  float c01 = p[(z0*8+y1)*8+x0]*(1.f-wx) + p[(z0*8+y1)*8+x1]*wx;
  float c10 = p[(z1*8+y0)*8+x0]*(1.f-wx) + p[(z1*8+y0)*8+x1]*wx;
  float c11 = p[(z1*8+y1)*8+x0]*(1.f-wx) + p[(z1*8+y1)*8+x1]*wx;
  float c0 = c00*(1.f-wy) + c01*wy;
  float c1 = c10*(1.f-wy) + c11*wy;
  return c0*(1.f-wz) + c1*wz;
}

// ---- K3: stageB = pw_kv+interp->Kb/Vt | pw_q->Qpk | interp_res ------------
__global__ __launch_bounds__(512) void stageB_kernel(
    const float* __restrict__ kvdw, const float* __restrict__ kv_pw,
    const float* __restrict__ qdw, const float* __restrict__ q_pw,
    const float* __restrict__ res8,
    unsigned short* __restrict__ Kb, unsigned short* __restrict__ Vt,
    unsigned short* __restrict__ Qpk, float* __restrict__ r16) {
  __shared__ float sm[2][512];
  int b = blockIdx.x;
  int tid = threadIdx.x;
  if (b < 128) {
    int kc0 = b * 2;
    int s = tid;
    float a0 = 0.f, a1 = 0.f;
    const float* w0 = kv_pw + (size_t)kc0 * 256;
    const float* w1 = w0 + 256;
    #pragma unroll 8
    for (int ic = 0; ic < 256; ic++) {
      float x = kvdw[(size_t)ic * 512 + s];
      a0 = fmaf(w0[ic], x, a0);
      a1 = fmaf(w1[ic], x, a1);
    }
    sm[0][s] = a0; sm[1][s] = a1;
    __syncthreads();
    #pragma unroll
    for (int r = 0; r < 16; r++) {
      int u  = r * 512 + tid;
      int cl = u >> 12, j = u & 4095;
      int z = j >> 8, y = (j >> 4) & 15, x = j & 15;
      int z0,z1,y0,y1,x0,x1; float wz,wy,wx;
      icoef8(z, z0, z1, wz); icoef8(y, y0, y1, wy); icoef8(x, x0, x1, wx);
      float val = trilin8(sm[cl], z0, z1, wz, y0, y1, wy, x0, x1, wx);
      __hip_bfloat16 bv = __float2bfloat16(val);
      unsigned short us = *reinterpret_cast<unsigned short*>(&bv);
      int kc = kc0 + cl;
      int c  = kc & 127;
      int head = c & 3, dh = c >> 2;
      if (kc < 128) {
        int k  = j & 31;
        int jp = (j & ~31) | (((k >> 3) << 2) + (k & 3) + ((k & 4) ? 16 : 0));
        Kb[((size_t)(head << 12) + jp) * 32 + dh] = us;
      } else {
        Vt[((size_t)(head * 32) + dh) * 4096 + j] = us;
      }
    }
  } else if (b < 256) {
    int bb   = b - 128;
    int head = bb >> 5;
    int r2   = bb & 31;
    int dh0  = (r2 >> 3) * 8;
    int i    = (r2 & 7) * 512 + tid;
    float acc[8];
    #pragma unroll
    for (int e = 0; e < 8; e++) acc[e] = 0.f;
    #pragma unroll 4
    for (int ic = 0; ic < 128; ic++) {
      float x = qdw[(size_t)ic * 4096 + i];
      #pragma unroll
      for (int e = 0; e < 8; e++)
        acc[e] = fmaf(q_pw[(size_t)((dh0 + e) * 4 + head) * 128 + ic], x, acc[e]);
    }
    i32x4 pk = { cvtpk(acc[0], acc[1]), cvtpk(acc[2], acc[3]),
                 cvtpk(acc[4], acc[5]), cvtpk(acc[6], acc[7]) };
    *reinterpret_cast<i32x4*>(Qpk + ((size_t)(head << 12) + i) * 32 + dh0) = pk;
  } else {
    int t = (b - 256) * 512 + tid;   // 524288
    int s = t & 4095, c = t >> 12;
    int z = s >> 8, y = (s >> 4) & 15, x = s & 15;
    int z0,z1,y0,y1,x0,x1; float wz,wy,wx;
    icoef8(z, z0, z1, wz); icoef8(y, y0, y1, wy); icoef8(x, x0, x1, wx);
    r16[t] = trilin8(res8 + c * 512, z0, z1, wz, y0, y1, wy, x0, x1, wx);
  }
}

// ---- K4: MFMA flash attention, 64-key iterations, LDS-shared K/V ----------
// 16-way K-split: grid 2048 = head(4) x qgroup(32) x ksplit(16); each block
// covers 4 x 64-key tiles (256 keys). Halved block time cuts the scheduling
// tail (1024 blocks @ 3/CU = 2 rounds, 2nd 1/3-full -> 2048 @ T/2 = ~1.33T).
__global__ __launch_bounds__(512, 6) void attn_mfma_kernel(
    const unsigned short* __restrict__ Qpk, const unsigned short* __restrict__ Kb,
    const unsigned short* __restrict__ Vt, const float* __restrict__ table,
    float* __restrict__ part_o, float* __restrict__ part_m, float* __restrict__ part_l) {
  __shared__ float lut[992];
  __shared__ unsigned short kvs[2][4096];  // per buf: K 64x32 (2048) | V 32x64 (2048)

  int head = blockIdx.x >> 9;
  int rem  = blockIdx.x & 511;
  int qg   = rem >> 4;
  int ksb  = rem & 15;
  int tid  = threadIdx.x;

  for (int u = tid; u < 991; u += 512) {
    int p = (u < 15) ? (u - 15 + 29791) : (u - 15);
    lut[u] = table[p * 4 + head] * SL;
  }

  int w    = tid >> 6;
  int lane = tid & 63;
  int qrow = lane & 15;
  int g    = lane >> 4;
  int i    = qg * 128 + w * 16 + qrow;       // query index for m/l bookkeeping
  int iz = i >> 8, iy = (i >> 4) & 15, ix = i & 15;
  int lanebase = iz * 31 + iy + ix;
  int gof = ((g >= 2) ? 15 : 0) - 8 * g;     // permuted-key bias offset

  bf16x8 qf = *(const bf16x8*)(Qpk + ((size_t)(head << 12) + i) * 32 + g * 8);

  const unsigned short* Kh = Kb + (size_t)head * 4096 * 32;
  const unsigned short* Vh = Vt + (size_t)head * 32 * 4096;

  int kt64 = ksb * 4;                        // first 64-key tile of this slice

  // staging source (swizzled global addr); LDS dst is linear tid*8 ushorts
  const unsigned short* src;
  size_t sstride;
  if (tid < 256) {
    int key = tid >> 2, s = tid & 3;         // key 0..63, dh-slot 0..3
    int gp  = s ^ ((key >> 1) & 3);
    src = Kh + (size_t)(kt64 * 64 + key) * 32 + gp * 8;
    sstride = 64 * 32;
  } else {
    int tt = tid - 256;
    int dh = tt >> 3, s = tt & 7;            // dh 0..31, key-slot 0..7
    int kg = s ^ (dh & 7);
    src = Vh + (size_t)dh * 4096 + kt64 * 64 + kg * 8;
    sstride = 64;
  }
  int t8 = tid * 8;                          // linear LDS dst (ushorts)

  // read-side swizzled offsets (constant per lane)
  int sw    = (qrow >> 1) & 3;
  int k0off = qrow * 32 + ((g ^ sw) * 8);    // K row-group stride 512 (16 rows)
  int q7    = qrow & 7;
  int v00 = 2048 + qrow * 64        + (((0 + g) ^ q7) * 8);
  int v01 = 2048 + (16 + qrow) * 64 + (((0 + g) ^ q7) * 8);
  int v10 = 2048 + qrow * 64        + (((4 + g) ^ q7) * 8);
  int v11 = 2048 + (16 + qrow) * 64 + (((4 + g) ^ q7) * 8);

  // prologue: stage tile 0 into buf 0
  {
    bf16x8 s0 = *(const bf16x8*)src; src += sstride;
    *(bf16x8*)(&kvs[0][t8]) = s0;
  }
  __syncthreads();

  f32x4 zero = {0.f, 0.f, 0.f, 0.f};
  f32x4 accO0 = zero, accO1 = zero;
  float m2 = -1e30f, lpart = 0.f;
  int cur = 0;

  for (int it = 0; it < 4; it++) {
    bf16x8 stg;
    if (it < 3) { stg = *(const bf16x8*)src; src += sstride; }

    const unsigned short* kb = &kvs[cur][0];
    bf16x8 kfA = *(const bf16x8*)(kb + k0off);
    bf16x8 kfB = *(const bf16x8*)(kb + k0off + 512);
    bf16x8 kfC = *(const bf16x8*)(kb + k0off + 1024);
    bf16x8 kfD = *(const bf16x8*)(kb + k0off + 1536);
    bf16x8 vf00 = *(const bf16x8*)(kb + v00);
    bf16x8 vf01 = *(const bf16x8*)(kb + v01);
    bf16x8 vf10 = *(const bf16x8*)(kb + v10);
    bf16x8 vf11 = *(const bf16x8*)(kb + v11);

    f32x4 accA = __builtin_amdgcn_mfma_f32_16x16x32_bf16(kfA, qf, zero, 0, 0, 0);
    f32x4 accB = __builtin_amdgcn_mfma_f32_16x16x32_bf16(kfB, qf, zero, 0, 0, 0);
    f32x4 accC = __builtin_amdgcn_mfma_f32_16x16x32_bf16(kfC, qf, zero, 0, 0, 0);
    f32x4 accD = __builtin_amdgcn_mfma_f32_16x16x32_bf16(kfD, qf, zero, 0, 0, 0);

    // bias for the two 32-key chunks of this tile (kt in [0,128))
    int kt  = ksb * 8 + it * 2;
    int za  = kt >> 3,        ya = (kt << 1) & 15;
    int zb  = (kt + 1) >> 3,  yb = ((kt + 1) << 1) & 15;
    const float* lp0 = &lut[lanebase + (495 - 31 * za - ya) + gof - 7];
    const float* lp1 = &lut[lanebase + (495 - 31 * zb - yb) + gof - 7];

    float t0 = fmaf(accA[0], SL, lp0[7]);
    float t1 = fmaf(accA[1], SL, lp0[6]);
    float t2 = fmaf(accA[2], SL, lp0[5]);
    float t3 = fmaf(accA[3], SL, lp0[4]);
    float t4 = fmaf(accB[0], SL, lp0[3]);
    float t5 = fmaf(accB[1], SL, lp0[2]);
    float t6 = fmaf(accB[2], SL, lp0[1]);
    float t7 = fmaf(accB[3], SL, lp0[0]);
    float t8v  = fmaf(accC[0], SL, lp1[7]);
    float t9   = fmaf(accC[1], SL, lp1[6]);
    float t10  = fmaf(accC[2], SL, lp1[5]);
    float t11  = fmaf(accC[3], SL, lp1[4]);
    float t12  = fmaf(accD[0], SL, lp1[3]);
    float t13  = fmaf(accD[1], SL, lp1[2]);
    float t14  = fmaf(accD[2], SL, lp1[1]);
    float t15  = fmaf(accD[3], SL, lp1[0]);

    // 16-way max, v_max3-fusible triples
    float x0 = fmaxf(fmaxf(t0, t1), t2);
    float x1 = fmaxf(fmaxf(t3, t4), t5);
    float x2 = fmaxf(fmaxf(t6, t7), t8v);
    float x3 = fmaxf(fmaxf(t9, t10), t11);
    float x4 = fmaxf(fmaxf(t12, t13), t14);
    float cm = fmaxf(fmaxf(fmaxf(x0, x1), x2), fmaxf(fmaxf(x3, x4), t15));
    cm = fmaxf(cm, __shfl_xor(cm, 16, 64));
    cm = fmaxf(cm, __shfl_xor(cm, 32, 64));

    if (__any(cm > m2 + 8.f)) {
      float mn   = fmaxf(m2, cm);
      float corr = exp2f(m2 - mn);          // per-row q = qrow
      m2 = mn;
      lpart *= corr;
      float c0 = __shfl(corr, g * 4 + 0, 64);
      float c1 = __shfl(corr, g * 4 + 1, 64);
      float c2 = __shfl(corr, g * 4 + 2, 64);
      float c3 = __shfl(corr, g * 4 + 3, 64);
      accO0[0] *= c0; accO0[1] *= c1; accO0[2] *= c2; accO0[3] *= c3;
      accO1[0] *= c0; accO1[1] *= c1; accO1[2] *= c2; accO1[3] *= c3;
    }

    float p0 = exp2f(t0 - m2),  p1 = exp2f(t1 - m2);
    float p2 = exp2f(t2 - m2),  p3 = exp2f(t3 - m2);
    float p4 = exp2f(t4 - m2),  p5 = exp2f(t5 - m2);
    float p6 = exp2f(t6 - m2),  p7 = exp2f(t7 - m2);
    float p8 = exp2f(t8v - m2), p9 = exp2f(t9 - m2);
    float p10 = exp2f(t10 - m2), p11 = exp2f(t11 - m2);
    float p12 = exp2f(t12 - m2), p13 = exp2f(t13 - m2);
    float p14 = exp2f(t14 - m2), p15 = exp2f(t15 - m2);
    lpart += (((p0 + p1) + (p2 + p3)) + ((p4 + p5) + (p6 + p7)))
           + (((p8 + p9) + (p10 + p11)) + ((p12 + p13) + (p14 + p15)));

    union { i32x4 i4; bf16x8 s8; } pa0, pa1;
    pa0.i4 = (i32x4){ cvtpk(p0, p1),  cvtpk(p2, p3),
                      cvtpk(p4, p5),  cvtpk(p6, p7) };
    pa1.i4 = (i32x4){ cvtpk(p8, p9),  cvtpk(p10, p11),
                      cvtpk(p12, p13), cvtpk(p14, p15) };

    accO0 = __builtin_amdgcn_mfma_f32_16x16x32_bf16(pa0.s8, vf00, accO0, 0, 0, 0);
    accO1 = __builtin_amdgcn_mfma_f32_16x16x32_bf16(pa0.s8, vf01, accO1, 0, 0, 0);
    accO0 = __builtin_amdgcn_mfma_f32_16x16x32_bf16(pa1.s8, vf10, accO0, 0, 0, 0);
    accO1 = __builtin_amdgcn_mfma_f32_16x16x32_bf16(pa1.s8, vf11, accO1, 0, 0, 0);

    if (it < 3) *(bf16x8*)(&kvs[cur ^ 1][t8]) = stg;
    __syncthreads();
    cur ^= 1;
  }

  float lsum = lpart + __shfl_xor(lpart, 16, 64);
  lsum += __shfl_xor(lsum, 32, 64);

  // partial write: accO0[r] = O[q = g*4+r][d = qrow], accO1 -> d = 16+qrow
  int base = head * 16 + ksb;
  if (g == 0) {
    part_m[base * 4096 + i] = m2;
    part_l[base * 4096 + i] = lsum;
  }
  int i0 = qg * 128 + w * 16 + g * 4;        // 4-aligned query base
  *(f32x4*)&part_o[(size_t)(base * 32 + qrow) * 4096 + i0]      = accO0;
  *(f32x4*)&part_o[(size_t)(base * 32 + 16 + qrow) * 4096 + i0] = accO1;
}

// ---- K4b: combine the 16 key-slice partials, write channel-spatial --------
__global__ __launch_bounds__(256) void attn_reduce_kernel(
    const float* __restrict__ part_o, const float* __restrict__ part_m,
    const float* __restrict__ part_l, float* __restrict__ o_sp) {
  int t = blockIdx.x * 256 + threadIdx.x;  // 65536
  int i = t & 4095;
  int rem = t >> 12;                       // 0..15
  int head = rem >> 2;
  int dg   = rem & 3;
  float mk[16], mx = -1e30f;
  #pragma unroll
  for (int ks = 0; ks < 16; ks++) { mk[ks] = part_m[(head*16+ks)*4096 + i]; mx = fmaxf(mx, mk[ks]); }
  float c[16], L = 0.f;
  #pragma unroll
  for (int ks = 0; ks < 16; ks++) {
    c[ks] = exp2f(mk[ks] - mx);
    L = fmaf(c[ks], part_l[(head*16+ks)*4096 + i], L);
  }
  float invL = 1.f / L;
  #pragma unroll
  for (int r = 0; r < 8; r++) {
    int d = dg * 8 + r;
    float acc = 0.f;
    #pragma unroll
    for (int ks = 0; ks < 16; ks++)
      acc = fmaf(c[ks], part_o[(size_t)((head*16+ks)*32 + d) * 4096 + i], acc);
    o_sp[(size_t)(d * 4 + head) * 4096 + i] = acc * invL;
  }
}

// ---- K5: depthwise out projection (2 outputs/thread) ----------------------
__global__ __launch_bounds__(256) void dw_out_kernel(
    const float* __restrict__ in, const float* __restrict__ w, float* __restrict__ out) {
  dw_body2<false>(in, w, nullptr, out, 16, 256, 4096, 128, blockIdx.x * 256 + threadIdx.x);
}

// ---- K6: pw_out 128->128 (VEC=2, 512 blocks) + r16 residue + BN sums ------
__global__ __launch_bounds__(256) void pw_out_kernel(
    const float* __restrict__ in, const float* __restrict__ w,
    const float* __restrict__ r16, float* __restrict__ res2,
    float* __restrict__ sums) {
  __shared__ float red[4][2][2];
  int oc0 = (blockIdx.x >> 3) * 2;
  int sb  = blockIdx.x & 7;
  int s0  = (sb * 256 + threadIdx.x) * 2;
  float a00 = 0.f, a01 = 0.f, a10 = 0.f, a11 = 0.f;
  const float* w0 = w + (size_t)oc0 * 128;
  const float* w1 = w0 + 128;
  #pragma unroll 8
  for (int ic = 0; ic < 128; ic++) {
    float xa = in[(size_t)ic * 4096 + s0];
    float xb = in[(size_t)ic * 4096 + s0 + 1];
    float wv0 = w0[ic], wv1 = w1[ic];
    a00 = fmaf(wv0, xa, a00); a01 = fmaf(wv0, xb, a01);
    a10 = fmaf(wv1, xa, a10); a11 = fmaf(wv1, xb, a11);
  }
  size_t ob0 = (size_t)oc0 * 4096 + s0;
  size_t ob1 = ob0 + 4096;
  float r00 = a00 + r16[ob0],     r01 = a01 + r16[ob0 + 1];
  float r10 = a10 + r16[ob1],     r11 = a11 + r16[ob1 + 1];
  res2[ob0] = r00; res2[ob0 + 1] = r01;
  res2[ob1] = r10; res2[ob1 + 1] = r11;
  float s_0 = r00 + r01, q_0 = fmaf(r00, r00, r01 * r01);
  float s_1 = r10 + r11, q_1 = fmaf(r10, r10, r11 * r11);
  #pragma unroll
  for (int off = 32; off; off >>= 1) {
    s_0 += __shfl_down(s_0, off, 64); q_0 += __shfl_down(q_0, off, 64);
    s_1 += __shfl_down(s_1, off, 64); q_1 += __shfl_down(q_1, off, 64);
  }
  int wid = threadIdx.x >> 6;
  if ((threadIdx.x & 63) == 0) {
    red[wid][0][0] = s_0; red[wid][0][1] = q_0;
    red[wid][1][0] = s_1; red[wid][1][1] = q_1;
  }
  __syncthreads();
  if (threadIdx.x < 2) {
    int o = threadIdx.x;
    float st = red[0][o][0] + red[1][o][0] + red[2][o][0] + red[3][o][0];
    float qt = red[0][o][1] + red[1][o][1] + red[2][o][1] + red[3][o][1];
    sums[(oc0 + o) * 8 + sb]        = st;
    sums[1024 + (oc0 + o) * 8 + sb] = qt;
  }
}

// ---- K7: mlp pw (VEC=2, 512 blocks) w/ BN-affine finalize + ReLU + residual
__global__ __launch_bounds__(256) void pw_mlp_kernel(
    const float* __restrict__ res2, const float* __restrict__ w,
    const float* __restrict__ gamma2, const float* __restrict__ beta2,
    const float* __restrict__ sums, float* __restrict__ out) {
  __shared__ float A[128], Bb[128];
  if (threadIdx.x < 128) {
    int c = threadIdx.x;
    float s = 0.f, q = 0.f;
    #pragma unroll
    for (int sb = 0; sb < 8; sb++) { s += sums[c * 8 + sb]; q += sums[1024 + c * 8 + sb]; }
    float m   = s * (1.0f / 4096.0f);
    float var = q * (1.0f / 4096.0f) - m * m;
    float a   = gamma2[c] * rsqrtf(var + 1e-5f);
    A[c]  = a;
    Bb[c] = beta2[c] - m * a;
  }
  __syncthreads();
  int oc0 = (blockIdx.x >> 3) * 2;
  int sb  = blockIdx.x & 7;
  int s0  = (sb * 256 + threadIdx.x) * 2;
  float a00 = 0.f, a01 = 0.f, a10 = 0.f, a11 = 0.f;
  const float* w0 = w + (size_t)oc0 * 128;
  const float* w1 = w0 + 128;
  #pragma unroll 8
  for (int ic = 0; ic < 128; ic++) {
    float aa = A[ic], bb = Bb[ic];
    float xa = fmaxf(fmaf(res2[(size_t)ic * 4096 + s0], aa, bb), 0.f);
    float xb = fmaxf(fmaf(res2[(size_t)ic * 4096 + s0 + 1], aa, bb), 0.f);
    float wv0 = w0[ic], wv1 = w1[ic];
    a00 = fmaf(wv0, xa, a00); a01 = fmaf(wv0, xb, a01);
    a10 = fmaf(wv1, xa, a10); a11 = fmaf(wv1, xb, a11);
  }
  size_t ob0 = (size_t)oc0 * 4096 + s0;
  size_t ob1 = ob0 + 4096;
  out[ob0]     = a00 + res2[ob0];
  out[ob0 + 1] = a01 + res2[ob0 + 1];
  out[ob1]     = a10 + res2[ob1];
  out[ob1 + 1] = a11 + res2[ob1 + 1];
}

// ---------------------------------------------------------------------------
extern "C" void kernel_launch(void* const* d_in, const int* in_sizes, int n_in,
                              void* d_out, int out_size, void* d_ws, size_t ws_size,
                              hipStream_t stream) {
  (void)in_sizes; (void)n_in; (void)out_size; (void)ws_size;
  const float* x1      = (const float*)d_in[0];
  const float* x2      = (const float*)d_in[1];
  const float* w_ch    = (const float*)d_in[2];
  const float* b_ch    = (const float*)d_in[3];
  const float* gamma_l = (const float*)d_in[4];
  const float* beta_l  = (const float*)d_in[5];
  const float* gamma_h = (const float*)d_in[6];
  const float* beta_h  = (const float*)d_in[7];
  const float* gamma2  = (const float*)d_in[8];
  const float* beta2   = (const float*)d_in[9];
  const float* kv_dw   = (const float*)d_in[10];
  const float* kv_pw   = (const float*)d_in[11];
  const float* q_dw    = (const float*)d_in[12];
  const float* q_pw    = (const float*)d_in[13];
  const float* out_dw  = (const float*)d_in[14];
  const float* out_pw  = (const float*)d_in[15];
  const float* w_mlp   = (const float*)d_in[16];
  const float* rtab    = (const float*)d_in[17];

  float* ws = (float*)d_ws;
  float* ab_l = ws + 0;        //    512
  float* ab_h = ws + 512;      //    256
  float* sums = ws + 768;      //   2048
  float* res8 = ws + 2816;     //  65536
  float* kvdw = ws + 68352;    // 131072
  float* qdw  = ws + 199424;   // 524288 -> 723712
  unsigned short* Qpk = (unsigned short*)(ws + 723712);   // 262144 f -> 985856
  unsigned short* Kb  = (unsigned short*)(ws + 985856);   // 262144 f -> 1248000
  unsigned short* Vt  = (unsigned short*)(ws + 1248000);  // 262144 f -> 1510144
  float* r16  = ws + 1510144;  // 524288 -> 2034432
  float* o_sp = ws + 2034432;  // 524288 -> 2558720
  float* odw  = ws + 2558720;  // 524288 -> 3083008
  float* res2 = ws + 3083008;  // 524288 -> 3607296
  float* part_o = ws + 3607296; // 16 splits: 64*32*4096 = 8388608 -> 11995904
  float* part_m = ws + 11995904; // 64*4096 = 262144 -> 12258048
  float* part_l = ws + 12258048; // 262144 -> 12520192 floats (~50.1 MB)

  bnstat_both_kernel<<<384, 256, 0, stream>>>(x1, x2, gamma_l, beta_l, gamma_h, beta_h,
                                              ab_l, ab_h);
  stageA_kernel<<<1408, 256, 0, stream>>>(x1, x2, w_ch, b_ch, kv_dw, q_dw,
                                          ab_l, ab_h, res8, kvdw, qdw);
  stageB_kernel<<<1280, 512, 0, stream>>>(kvdw, kv_pw, qdw, q_pw, res8,
                                          Kb, Vt, Qpk, r16);
  attn_mfma_kernel<<<2048, 512, 0, stream>>>(Qpk, Kb, Vt, rtab,
                                             part_o, part_m, part_l);
  attn_reduce_kernel<<<256, 256, 0, stream>>>(part_o, part_m, part_l, o_sp);
  dw_out_kernel<<<1024, 256, 0, stream>>>(o_sp, out_dw, odw);
  pw_out_kernel<<<512, 256, 0, stream>>>(odw, out_pw, r16, res2, sums);
  pw_mlp_kernel<<<512, 256, 0, stream>>>(res2, w_mlp, gamma2, beta2, sums, (float*)d_out);
}

// Round 22
// 102.637 us; speedup vs baseline: 1.3003x; 1.3003x over previous
//
#include <hip/hip_runtime.h>
#include <hip/hip_bf16.h>

using f32x4  = __attribute__((ext_vector_type(4))) float;
using bf16x8 = __attribute__((ext_vector_type(8))) short;
using i32x4  = __attribute__((ext_vector_type(4))) int;

static constexpr float SCALE = 0.17677669529663687f; // 32^-0.5
static constexpr float L2E   = 1.4426950408889634f;
static constexpr float SL    = SCALE * L2E;

__device__ inline int cvtpk(float lo, float hi) {
  int r;
  asm("v_cvt_pk_bf16_f32 %0,%1,%2" : "=v"(r) : "v"(lo), "v"(hi));
  return r;
}

// ---- wave+block reduce (sum, sumsq), 256-thread blocks --------------------
__device__ inline void bred2(float& s, float& ss) {
  #pragma unroll
  for (int off = 32; off; off >>= 1) {
    s  += __shfl_down(s, off, 64);
    ss += __shfl_down(ss, off, 64);
  }
  __shared__ float as_[4], ass_[4];
  int wid = threadIdx.x >> 6;
  if ((threadIdx.x & 63) == 0) { as_[wid] = s; ass_[wid] = ss; }
  __syncthreads();
  s  = as_[0] + as_[1] + as_[2] + as_[3];
  ss = ass_[0] + ass_[1] + ass_[2] + ass_[3];
}

// ---- K1: BN stats for x1 and x2 -------------------------------------------
__global__ __launch_bounds__(256) void bnstat_both_kernel(
    const float* __restrict__ x1, const float* __restrict__ x2,
    const float* __restrict__ gl, const float* __restrict__ bl,
    const float* __restrict__ gh, const float* __restrict__ bh,
    float* __restrict__ ab_l, float* __restrict__ ab_h) {
  int b = blockIdx.x;
  const float* src; const float *gamma, *beta; float* ab; int S, C, c;
  if (b < 256) { c = b;       src = x1 + (size_t)c * 512;  S = 512;  C = 256; gamma = gl; beta = bl; ab = ab_l; }
  else         { c = b - 256; src = x2 + (size_t)c * 4096; S = 4096; C = 128; gamma = gh; beta = bh; ab = ab_h; }
  float s = 0.f, ss = 0.f;
  for (int i = threadIdx.x; i < S; i += 256) { float v = src[i]; s += v; ss = fmaf(v, v, ss); }
  bred2(s, ss);
  if (threadIdx.x == 0) {
    float inv = 1.0f / (float)S;
    float m   = s * inv;
    float var = ss * inv - m * m;
    float a   = gamma[c] * rsqrtf(var + 1e-5f);
    ab[c]     = a;
    ab[C + c] = beta[c] - m * a;
  }
}

// ---- depthwise 3x3x3, 2 x-adjacent outputs per thread ---------------------
template<bool AFF>
__device__ inline void dw_body2(
    const float* __restrict__ in, const float* __restrict__ w,
    const float* __restrict__ ab, float* __restrict__ out,
    int n, int nn, int n3, int C, int t2) {
  int half = n3 >> 1;
  int c  = t2 / half;
  int sp = (t2 - c * half) * 2;            // even spatial index
  int z = sp / nn, r = sp - z * nn, y = r / n, x = r - y * n;  // x even
  const float* src = in + (size_t)c * n3;
  const float* wc  = w + c * 27;
  float a = 1.f, b = 0.f;
  if (AFF) { a = ab[c]; b = ab[C + c]; }
  float acc0 = 0.f, acc1 = 0.f;
  #pragma unroll
  for (int kd = 0; kd < 3; kd++) {
    int zz = z + kd - 1;
    if (zz < 0 || zz >= n) continue;
    #pragma unroll
    for (int kh = 0; kh < 3; kh++) {
      int yy = y + kh - 1;
      if (yy < 0 || yy >= n) continue;
      const float* row = src + (zz * n + yy) * n;
      const float* wr  = wc + kd * 9 + kh * 3;
      float v1 = row[x];
      float v2 = row[x + 1];
      float v0 = (x >= 1)     ? row[x - 1] : 0.f;
      float v3 = (x + 2 < n)  ? row[x + 2] : 0.f;
      if (AFF) {
        if (x >= 1)    v0 = fmaf(v0, a, b);
        v1 = fmaf(v1, a, b);
        v2 = fmaf(v2, a, b);
        if (x + 2 < n) v3 = fmaf(v3, a, b);
      }
      float w0 = wr[0], w1 = wr[1], w2 = wr[2];
      acc0 = fmaf(v0, w0, fmaf(v1, w1, fmaf(v2, w2, acc0)));
      acc1 = fmaf(v1, w0, fmaf(v2, w1, fmaf(v3, w2, acc1)));
    }
  }
  out[(size_t)c * n3 + sp]     = acc0;
  out[(size_t)c * n3 + sp + 1] = acc1;
}

// ---- K2: stageA = res8 pointwise | dw_kv | dw_q ---------------------------
__global__ __launch_bounds__(256) void stageA_kernel(
    const float* __restrict__ x1, const float* __restrict__ x2,
    const float* __restrict__ w_ch, const float* __restrict__ b_ch,
    const float* __restrict__ kv_dw, const float* __restrict__ q_dw,
    const float* __restrict__ ab_l, const float* __restrict__ ab_h,
    float* __restrict__ res8, float* __restrict__ kvdw, float* __restrict__ qdw) {
  int b = blockIdx.x;
  if (b < 128) {
    int oc0 = (b >> 1) * 2;
    int s   = (b & 1) * 256 + threadIdx.x;
    float a0 = 0.f, a1 = 0.f;
    const float* w0 = w_ch + (size_t)oc0 * 256;
    const float* w1 = w0 + 256;
    #pragma unroll 8
    for (int ic = 0; ic < 256; ic++) {
      float x = x1[(size_t)ic * 512 + s];
      a0 = fmaf(w0[ic], x, a0);
      a1 = fmaf(w1[ic], x, a1);
    }
    res8[(size_t)oc0 * 512 + s]       = a0 + b_ch[oc0];
    res8[(size_t)(oc0 + 1) * 512 + s] = a1 + b_ch[oc0 + 1];
  } else if (b < 384) {
    dw_body2<true>(x1, kv_dw, ab_l, kvdw, 8, 64, 512, 256, (b - 128) * 256 + threadIdx.x);
  } else {
    dw_body2<true>(x2, q_dw, ab_h, qdw, 16, 256, 4096, 128, (b - 384) * 256 + threadIdx.x);
  }
}

// ---- trilinear helpers ----------------------------------------------------
__device__ inline void icoef8(int o, int& lo, int& hi, float& w) {
  float p = (float)o * (7.0f / 15.0f);
  int l = (int)floorf(p);
  if (l > 7) l = 7;
  int h = l + 1 > 7 ? 7 : l + 1;
  w  = p - (float)l;
  lo = l; hi = h;
}

__device__ inline float trilin8(const float* __restrict__ p,
                                int z0, int z1, float wz,
                                int y0, int y1, float wy,
                                int x0, int x1, float wx) {
  float c00 = p[(z0*8+y0)*8+x0]*(1.f-wx) + p[(z0*8+y0)*8+x1]*wx;
  float c01 = p[(z0*8+y1)*8+x0]*(1.f-wx) + p[(z0*8+y1)*8+x1]*wx;
  float c10 = p[(z1*8+y0)*8+x0]*(1.f-wx) + p[(z1*8+y0)*8+x1]*wx;
  float c11 = p[(z1*8+y1)*8+x0]*(1.f-wx) + p[(z1*8+y1)*8+x1]*wx;
  float c0 = c00*(1.f-wy) + c01*wy;
  float c1 = c10*(1.f-wy) + c11*wy;
  return c0*(1.f-wz) + c1*wz;
}

// ---- K3: stageB = pw_kv+interp->Kb/Vt | pw_q->Qpk | interp_res ------------
__global__ __launch_bounds__(512) void stageB_kernel(
    const float* __restrict__ kvdw, const float* __restrict__ kv_pw,
    const float* __restrict__ qdw, const float* __restrict__ q_pw,
    const float* __restrict__ res8,
    unsigned short* __restrict__ Kb, unsigned short* __restrict__ Vt,
    unsigned short* __restrict__ Qpk, float* __restrict__ r16) {
  __shared__ float sm[2][512];
  int b = blockIdx.x;
  int tid = threadIdx.x;
  if (b < 128) {
    int kc0 = b * 2;
    int s = tid;
    float a0 = 0.f, a1 = 0.f;
    const float* w0 = kv_pw + (size_t)kc0 * 256;
    const float* w1 = w0 + 256;
    #pragma unroll 8
    for (int ic = 0; ic < 256; ic++) {
      float x = kvdw[(size_t)ic * 512 + s];
      a0 = fmaf(w0[ic], x, a0);
      a1 = fmaf(w1[ic], x, a1);
    }
    sm[0][s] = a0; sm[1][s] = a1;
    __syncthreads();
    #pragma unroll
    for (int r = 0; r < 16; r++) {
      int u  = r * 512 + tid;
      int cl = u >> 12, j = u & 4095;
      int z = j >> 8, y = (j >> 4) & 15, x = j & 15;
      int z0,z1,y0,y1,x0,x1; float wz,wy,wx;
      icoef8(z, z0, z1, wz); icoef8(y, y0, y1, wy); icoef8(x, x0, x1, wx);
      float val = trilin8(sm[cl], z0, z1, wz, y0, y1, wy, x0, x1, wx);
      __hip_bfloat16 bv = __float2bfloat16(val);
      unsigned short us = *reinterpret_cast<unsigned short*>(&bv);
      int kc = kc0 + cl;
      int c  = kc & 127;
      int head = c & 3, dh = c >> 2;
      if (kc < 128) {
        int k  = j & 31;
        int jp = (j & ~31) | (((k >> 3) << 2) + (k & 3) + ((k & 4) ? 16 : 0));
        Kb[((size_t)(head << 12) + jp) * 32 + dh] = us;
      } else {
        Vt[((size_t)(head * 32) + dh) * 4096 + j] = us;
      }
    }
  } else if (b < 256) {
    int bb   = b - 128;
    int head = bb >> 5;
    int r2   = bb & 31;
    int dh0  = (r2 >> 3) * 8;
    int i    = (r2 & 7) * 512 + tid;
    float acc[8];
    #pragma unroll
    for (int e = 0; e < 8; e++) acc[e] = 0.f;
    #pragma unroll 4
    for (int ic = 0; ic < 128; ic++) {
      float x = qdw[(size_t)ic * 4096 + i];
      #pragma unroll
      for (int e = 0; e < 8; e++)
        acc[e] = fmaf(q_pw[(size_t)((dh0 + e) * 4 + head) * 128 + ic], x, acc[e]);
    }
    i32x4 pk = { cvtpk(acc[0], acc[1]), cvtpk(acc[2], acc[3]),
                 cvtpk(acc[4], acc[5]), cvtpk(acc[6], acc[7]) };
    *reinterpret_cast<i32x4*>(Qpk + ((size_t)(head << 12) + i) * 32 + dh0) = pk;
  } else {
    int t = (b - 256) * 512 + tid;   // 524288
    int s = t & 4095, c = t >> 12;
    int z = s >> 8, y = (s >> 4) & 15, x = s & 15;
    int z0,z1,y0,y1,x0,x1; float wz,wy,wx;
    icoef8(z, z0, z1, wz); icoef8(y, y0, y1, wy); icoef8(x, x0, x1, wx);
    r16[t] = trilin8(res8 + c * 512, z0, z1, wz, y0, y1, wy, x0, x1, wx);
  }
}

// ---- K4: MFMA flash attention, 64-key iterations, LDS-shared K/V ----------
// __launch_bounds__(512, 6): ~84 VGPR budget (no spill), 3 blocks/CU.
__global__ __launch_bounds__(512, 6) void attn_mfma_kernel(
    const unsigned short* __restrict__ Qpk, const unsigned short* __restrict__ Kb,
    const unsigned short* __restrict__ Vt, const float* __restrict__ table,
    float* __restrict__ part_o, float* __restrict__ part_m, float* __restrict__ part_l) {
  __shared__ float lut[992];
  __shared__ unsigned short kvs[2][4096];  // per buf: K 64x32 (2048) | V 32x64 (2048)

  int head = blockIdx.x >> 8;
  int rem  = blockIdx.x & 255;
  int qg   = rem >> 3;
  int ksb  = rem & 7;
  int tid  = threadIdx.x;

  for (int u = tid; u < 991; u += 512) {
    int p = (u < 15) ? (u - 15 + 29791) : (u - 15);
    lut[u] = table[p * 4 + head] * SL;
  }

  int w    = tid >> 6;
  int lane = tid & 63;
  int qrow = lane & 15;
  int g    = lane >> 4;
  int i    = qg * 128 + w * 16 + qrow;       // query index for m/l bookkeeping
  int iz = i >> 8, iy = (i >> 4) & 15, ix = i & 15;
  int lanebase = iz * 31 + iy + ix;
  int gof = ((g >= 2) ? 15 : 0) - 8 * g;     // permuted-key bias offset

  bf16x8 qf = *(const bf16x8*)(Qpk + ((size_t)(head << 12) + i) * 32 + g * 8);

  const unsigned short* Kh = Kb + (size_t)head * 4096 * 32;
  const unsigned short* Vh = Vt + (size_t)head * 32 * 4096;

  int kt64 = ksb * 8;                        // first 64-key tile of this slice

  // staging source (swizzled global addr); LDS dst is linear tid*8 ushorts
  const unsigned short* src;
  size_t sstride;
  if (tid < 256) {
    int key = tid >> 2, s = tid & 3;         // key 0..63, dh-slot 0..3
    int gp  = s ^ ((key >> 1) & 3);
    src = Kh + (size_t)(kt64 * 64 + key) * 32 + gp * 8;
    sstride = 64 * 32;
  } else {
    int tt = tid - 256;
    int dh = tt >> 3, s = tt & 7;            // dh 0..31, key-slot 0..7
    int kg = s ^ (dh & 7);
    src = Vh + (size_t)dh * 4096 + kt64 * 64 + kg * 8;
    sstride = 64;
  }
  int t8 = tid * 8;                          // linear LDS dst (ushorts)

  // read-side swizzled offsets (constant per lane)
  int sw    = (qrow >> 1) & 3;
  int k0off = qrow * 32 + ((g ^ sw) * 8);    // K row-group stride 512 (16 rows)
  int q7    = qrow & 7;
  int v00 = 2048 + qrow * 64        + (((0 + g) ^ q7) * 8);
  int v01 = 2048 + (16 + qrow) * 64 + (((0 + g) ^ q7) * 8);
  int v10 = 2048 + qrow * 64        + (((4 + g) ^ q7) * 8);
  int v11 = 2048 + (16 + qrow) * 64 + (((4 + g) ^ q7) * 8);

  // prologue: stage tile 0 into buf 0
  {
    bf16x8 s0 = *(const bf16x8*)src; src += sstride;
    *(bf16x8*)(&kvs[0][t8]) = s0;
  }
  __syncthreads();

  f32x4 zero = {0.f, 0.f, 0.f, 0.f};
  f32x4 accO0 = zero, accO1 = zero;
  float m2 = -1e30f, lpart = 0.f;
  int cur = 0;

  for (int it = 0; it < 8; it++) {
    bf16x8 stg;
    if (it < 7) { stg = *(const bf16x8*)src; src += sstride; }

    const unsigned short* kb = &kvs[cur][0];
    bf16x8 kfA = *(const bf16x8*)(kb + k0off);
    bf16x8 kfB = *(const bf16x8*)(kb + k0off + 512);
    bf16x8 kfC = *(const bf16x8*)(kb + k0off + 1024);
    bf16x8 kfD = *(const bf16x8*)(kb + k0off + 1536);
    bf16x8 vf00 = *(const bf16x8*)(kb + v00);
    bf16x8 vf01 = *(const bf16x8*)(kb + v01);
    bf16x8 vf10 = *(const bf16x8*)(kb + v10);
    bf16x8 vf11 = *(const bf16x8*)(kb + v11);

    f32x4 accA = __builtin_amdgcn_mfma_f32_16x16x32_bf16(kfA, qf, zero, 0, 0, 0);
    f32x4 accB = __builtin_amdgcn_mfma_f32_16x16x32_bf16(kfB, qf, zero, 0, 0, 0);
    f32x4 accC = __builtin_amdgcn_mfma_f32_16x16x32_bf16(kfC, qf, zero, 0, 0, 0);
    f32x4 accD = __builtin_amdgcn_mfma_f32_16x16x32_bf16(kfD, qf, zero, 0, 0, 0);

    // bias for the two 32-key chunks of this tile
    int kt  = ksb * 16 + it * 2;
    int za  = kt >> 3,        ya = (kt << 1) & 15;
    int zb  = (kt + 1) >> 3,  yb = ((kt + 1) << 1) & 15;
    const float* lp0 = &lut[lanebase + (495 - 31 * za - ya) + gof - 7];
    const float* lp1 = &lut[lanebase + (495 - 31 * zb - yb) + gof - 7];

    float t0 = fmaf(accA[0], SL, lp0[7]);
    float t1 = fmaf(accA[1], SL, lp0[6]);
    float t2 = fmaf(accA[2], SL, lp0[5]);
    float t3 = fmaf(accA[3], SL, lp0[4]);
    float t4 = fmaf(accB[0], SL, lp0[3]);
    float t5 = fmaf(accB[1], SL, lp0[2]);
    float t6 = fmaf(accB[2], SL, lp0[1]);
    float t7 = fmaf(accB[3], SL, lp0[0]);
    float t8v  = fmaf(accC[0], SL, lp1[7]);
    float t9   = fmaf(accC[1], SL, lp1[6]);
    float t10  = fmaf(accC[2], SL, lp1[5]);
    float t11  = fmaf(accC[3], SL, lp1[4]);
    float t12  = fmaf(accD[0], SL, lp1[3]);
    float t13  = fmaf(accD[1], SL, lp1[2]);
    float t14  = fmaf(accD[2], SL, lp1[1]);
    float t15  = fmaf(accD[3], SL, lp1[0]);

    // 16-way max, v_max3-fusible triples
    float x0 = fmaxf(fmaxf(t0, t1), t2);
    float x1 = fmaxf(fmaxf(t3, t4), t5);
    float x2 = fmaxf(fmaxf(t6, t7), t8v);
    float x3 = fmaxf(fmaxf(t9, t10), t11);
    float x4 = fmaxf(fmaxf(t12, t13), t14);
    float cm = fmaxf(fmaxf(fmaxf(x0, x1), x2), fmaxf(fmaxf(x3, x4), t15));
    cm = fmaxf(cm, __shfl_xor(cm, 16, 64));
    cm = fmaxf(cm, __shfl_xor(cm, 32, 64));

    if (__any(cm > m2 + 8.f)) {
      float mn   = fmaxf(m2, cm);
      float corr = exp2f(m2 - mn);          // per-row q = qrow
      m2 = mn;
      lpart *= corr;
      float c0 = __shfl(corr, g * 4 + 0, 64);
      float c1 = __shfl(corr, g * 4 + 1, 64);
      float c2 = __shfl(corr, g * 4 + 2, 64);
      float c3 = __shfl(corr, g * 4 + 3, 64);
      accO0[0] *= c0; accO0[1] *= c1; accO0[2] *= c2; accO0[3] *= c3;
      accO1[0] *= c0; accO1[1] *= c1; accO1[2] *= c2; accO1[3] *= c3;
    }

    float p0 = exp2f(t0 - m2),  p1 = exp2f(t1 - m2);
    float p2 = exp2f(t2 - m2),  p3 = exp2f(t3 - m2);
    float p4 = exp2f(t4 - m2),  p5 = exp2f(t5 - m2);
    float p6 = exp2f(t6 - m2),  p7 = exp2f(t7 - m2);
    float p8 = exp2f(t8v - m2), p9 = exp2f(t9 - m2);
    float p10 = exp2f(t10 - m2), p11 = exp2f(t11 - m2);
    float p12 = exp2f(t12 - m2), p13 = exp2f(t13 - m2);
    float p14 = exp2f(t14 - m2), p15 = exp2f(t15 - m2);
    lpart += (((p0 + p1) + (p2 + p3)) + ((p4 + p5) + (p6 + p7)))
           + (((p8 + p9) + (p10 + p11)) + ((p12 + p13) + (p14 + p15)));

    union { i32x4 i4; bf16x8 s8; } pa0, pa1;
    pa0.i4 = (i32x4){ cvtpk(p0, p1),  cvtpk(p2, p3),
                      cvtpk(p4, p5),  cvtpk(p6, p7) };
    pa1.i4 = (i32x4){ cvtpk(p8, p9),  cvtpk(p10, p11),
                      cvtpk(p12, p13), cvtpk(p14, p15) };

    accO0 = __builtin_amdgcn_mfma_f32_16x16x32_bf16(pa0.s8, vf00, accO0, 0, 0, 0);
    accO1 = __builtin_amdgcn_mfma_f32_16x16x32_bf16(pa0.s8, vf01, accO1, 0, 0, 0);
    accO0 = __builtin_amdgcn_mfma_f32_16x16x32_bf16(pa1.s8, vf10, accO0, 0, 0, 0);
    accO1 = __builtin_amdgcn_mfma_f32_16x16x32_bf16(pa1.s8, vf11, accO1, 0, 0, 0);

    if (it < 7) *(bf16x8*)(&kvs[cur ^ 1][t8]) = stg;
    __syncthreads();
    cur ^= 1;
  }

  float lsum = lpart + __shfl_xor(lpart, 16, 64);
  lsum += __shfl_xor(lsum, 32, 64);

  // partial write: accO0[r] = O[q = g*4+r][d = qrow], accO1 -> d = 16+qrow
  int base = head * 8 + ksb;
  if (g == 0) {
    part_m[base * 4096 + i] = m2;
    part_l[base * 4096 + i] = lsum;
  }
  int i0 = qg * 128 + w * 16 + g * 4;        // 4-aligned query base
  *(f32x4*)&part_o[(size_t)(base * 32 + qrow) * 4096 + i0]      = accO0;
  *(f32x4*)&part_o[(size_t)(base * 32 + 16 + qrow) * 4096 + i0] = accO1;
}

// ---- K4b: combine the 8 key-slice partials, write channel-spatial ---------
__global__ __launch_bounds__(256) void attn_reduce_kernel(
    const float* __restrict__ part_o, const float* __restrict__ part_m,
    const float* __restrict__ part_l, float* __restrict__ o_sp) {
  int t = blockIdx.x * 256 + threadIdx.x;  // 65536
  int i = t & 4095;
  int rem = t >> 12;                       // 0..15
  int head = rem >> 2;
  int dg   = rem & 3;
  float mk[8], mx = -1e30f;
  #pragma unroll
  for (int ks = 0; ks < 8; ks++) { mk[ks] = part_m[(head*8+ks)*4096 + i]; mx = fmaxf(mx, mk[ks]); }
  float c[8], L = 0.f;
  #pragma unroll
  for (int ks = 0; ks < 8; ks++) {
    c[ks] = exp2f(mk[ks] - mx);
    L = fmaf(c[ks], part_l[(head*8+ks)*4096 + i], L);
  }
  float invL = 1.f / L;
  #pragma unroll
  for (int r = 0; r < 8; r++) {
    int d = dg * 8 + r;
    float acc = 0.f;
    #pragma unroll
    for (int ks = 0; ks < 8; ks++)
      acc = fmaf(c[ks], part_o[(size_t)((head*8+ks)*32 + d) * 4096 + i], acc);
    o_sp[(size_t)(d * 4 + head) * 4096 + i] = acc * invL;
  }
}

// ---- K5: depthwise out projection (2 outputs/thread) ----------------------
__global__ __launch_bounds__(256) void dw_out_kernel(
    const float* __restrict__ in, const float* __restrict__ w, float* __restrict__ out) {
  dw_body2<false>(in, w, nullptr, out, 16, 256, 4096, 128, blockIdx.x * 256 + threadIdx.x);
}

// ---- K6: pw_out 128->128 (VEC=2, 512 blocks) + r16 residue + BN sums ------
__global__ __launch_bounds__(256) void pw_out_kernel(
    const float* __restrict__ in, const float* __restrict__ w,
    const float* __restrict__ r16, float* __restrict__ res2,
    float* __restrict__ sums) {
  __shared__ float red[4][2][2];
  int oc0 = (blockIdx.x >> 3) * 2;
  int sb  = blockIdx.x & 7;
  int s0  = (sb * 256 + threadIdx.x) * 2;
  float a00 = 0.f, a01 = 0.f, a10 = 0.f, a11 = 0.f;
  const float* w0 = w + (size_t)oc0 * 128;
  const float* w1 = w0 + 128;
  #pragma unroll 8
  for (int ic = 0; ic < 128; ic++) {
    float xa = in[(size_t)ic * 4096 + s0];
    float xb = in[(size_t)ic * 4096 + s0 + 1];
    float wv0 = w0[ic], wv1 = w1[ic];
    a00 = fmaf(wv0, xa, a00); a01 = fmaf(wv0, xb, a01);
    a10 = fmaf(wv1, xa, a10); a11 = fmaf(wv1, xb, a11);
  }
  size_t ob0 = (size_t)oc0 * 4096 + s0;
  size_t ob1 = ob0 + 4096;
  float r00 = a00 + r16[ob0],     r01 = a01 + r16[ob0 + 1];
  float r10 = a10 + r16[ob1],     r11 = a11 + r16[ob1 + 1];
  res2[ob0] = r00; res2[ob0 + 1] = r01;
  res2[ob1] = r10; res2[ob1 + 1] = r11;
  float s_0 = r00 + r01, q_0 = fmaf(r00, r00, r01 * r01);
  float s_1 = r10 + r11, q_1 = fmaf(r10, r10, r11 * r11);
  #pragma unroll
  for (int off = 32; off; off >>= 1) {
    s_0 += __shfl_down(s_0, off, 64); q_0 += __shfl_down(q_0, off, 64);
    s_1 += __shfl_down(s_1, off, 64); q_1 += __shfl_down(q_1, off, 64);
  }
  int wid = threadIdx.x >> 6;
  if ((threadIdx.x & 63) == 0) {
    red[wid][0][0] = s_0; red[wid][0][1] = q_0;
    red[wid][1][0] = s_1; red[wid][1][1] = q_1;
  }
  __syncthreads();
  if (threadIdx.x < 2) {
    int o = threadIdx.x;
    float st = red[0][o][0] + red[1][o][0] + red[2][o][0] + red[3][o][0];
    float qt = red[0][o][1] + red[1][o][1] + red[2][o][1] + red[3][o][1];
    sums[(oc0 + o) * 8 + sb]        = st;
    sums[1024 + (oc0 + o) * 8 + sb] = qt;
  }
}

// ---- K7: mlp pw (VEC=2, 512 blocks) w/ BN-affine finalize + ReLU + residual
__global__ __launch_bounds__(256) void pw_mlp_kernel(
    const float* __restrict__ res2, const float* __restrict__ w,
    const float* __restrict__ gamma2, const float* __restrict__ beta2,
    const float* __restrict__ sums, float* __restrict__ out) {
  __shared__ float A[128], Bb[128];
  if (threadIdx.x < 128) {
    int c = threadIdx.x;
    float s = 0.f, q = 0.f;
    #pragma unroll
    for (int sb = 0; sb < 8; sb++) { s += sums[c * 8 + sb]; q += sums[1024 + c * 8 + sb]; }
    float m   = s * (1.0f / 4096.0f);
    float var = q * (1.0f / 4096.0f) - m * m;
    float a   = gamma2[c] * rsqrtf(var + 1e-5f);
    A[c]  = a;
    Bb[c] = beta2[c] - m * a;
  }
  __syncthreads();
  int oc0 = (blockIdx.x >> 3) * 2;
  int sb  = blockIdx.x & 7;
  int s0  = (sb * 256 + threadIdx.x) * 2;
  float a00 = 0.f, a01 = 0.f, a10 = 0.f, a11 = 0.f;
  const float* w0 = w + (size_t)oc0 * 128;
  const float* w1 = w0 + 128;
  #pragma unroll 8
  for (int ic = 0; ic < 128; ic++) {
    float aa = A[ic], bb = Bb[ic];
    float xa = fmaxf(fmaf(res2[(size_t)ic * 4096 + s0], aa, bb), 0.f);
    float xb = fmaxf(fmaf(res2[(size_t)ic * 4096 + s0 + 1], aa, bb), 0.f);
    float wv0 = w0[ic], wv1 = w1[ic];
    a00 = fmaf(wv0, xa, a00); a01 = fmaf(wv0, xb, a01);
    a10 = fmaf(wv1, xa, a10); a11 = fmaf(wv1, xb, a11);
  }
  size_t ob0 = (size_t)oc0 * 4096 + s0;
  size_t ob1 = ob0 + 4096;
  out[ob0]     = a00 + res2[ob0];
  out[ob0 + 1] = a01 + res2[ob0 + 1];
  out[ob1]     = a10 + res2[ob1];
  out[ob1 + 1] = a11 + res2[ob1 + 1];
}

// ---------------------------------------------------------------------------
extern "C" void kernel_launch(void* const* d_in, const int* in_sizes, int n_in,
                              void* d_out, int out_size, void* d_ws, size_t ws_size,
                              hipStream_t stream) {
  (void)in_sizes; (void)n_in; (void)out_size; (void)ws_size;
  const float* x1      = (const float*)d_in[0];
  const float* x2      = (const float*)d_in[1];
  const float* w_ch    = (const float*)d_in[2];
  const float* b_ch    = (const float*)d_in[3];
  const float* gamma_l = (const float*)d_in[4];
  const float* beta_l  = (const float*)d_in[5];
  const float* gamma_h = (const float*)d_in[6];
  const float* beta_h  = (const float*)d_in[7];
  const float* gamma2  = (const float*)d_in[8];
  const float* beta2   = (const float*)d_in[9];
  const float* kv_dw   = (const float*)d_in[10];
  const float* kv_pw   = (const float*)d_in[11];
  const float* q_dw    = (const float*)d_in[12];
  const float* q_pw    = (const float*)d_in[13];
  const float* out_dw  = (const float*)d_in[14];
  const float* out_pw  = (const float*)d_in[15];
  const float* w_mlp   = (const float*)d_in[16];
  const float* rtab    = (const float*)d_in[17];

  float* ws = (float*)d_ws;
  float* ab_l = ws + 0;        //    512
  float* ab_h = ws + 512;      //    256
  float* sums = ws + 768;      //   2048
  float* res8 = ws + 2816;     //  65536
  float* kvdw = ws + 68352;    // 131072
  float* qdw  = ws + 199424;   // 524288 -> 723712
  unsigned short* Qpk = (unsigned short*)(ws + 723712);   // 262144 f -> 985856
  unsigned short* Kb  = (unsigned short*)(ws + 985856);   // 262144 f -> 1248000
  unsigned short* Vt  = (unsigned short*)(ws + 1248000);  // 262144 f -> 1510144
  float* r16  = ws + 1510144;  // 524288 -> 2034432
  float* o_sp = ws + 2034432;  // 524288 -> 2558720
  float* odw  = ws + 2558720;  // 524288 -> 3083008
  float* res2 = ws + 3083008;  // 524288 -> 3607296
  float* part_o = ws + 3607296; // 4194304 -> 7801600
  float* part_m = ws + 7801600; // 131072  -> 7932672
  float* part_l = ws + 7932672; // 131072  -> 8063744 floats (~32.3 MB)

  bnstat_both_kernel<<<384, 256, 0, stream>>>(x1, x2, gamma_l, beta_l, gamma_h, beta_h,
                                              ab_l, ab_h);
  stageA_kernel<<<1408, 256, 0, stream>>>(x1, x2, w_ch, b_ch, kv_dw, q_dw,
                                          ab_l, ab_h, res8, kvdw, qdw);
  stageB_kernel<<<1280, 512, 0, stream>>>(kvdw, kv_pw, qdw, q_pw, res8,
                                          Kb, Vt, Qpk, r16);
  attn_mfma_kernel<<<1024, 512, 0, stream>>>(Qpk, Kb, Vt, rtab,
                                             part_o, part_m, part_l);
  attn_reduce_kernel<<<256, 256, 0, stream>>>(part_o, part_m, part_l, o_sp);
  dw_out_kernel<<<1024, 256, 0, stream>>>(o_sp, out_dw, odw);
  pw_out_kernel<<<512, 256, 0, stream>>>(odw, out_pw, r16, res2, sums);
  pw_mlp_kernel<<<512, 256, 0, stream>>>(res2, w_mlp, gamma2, beta2, sums, (float*)d_out);
}